// Round 8
// baseline (68.850 us; speedup 1.0000x reference)
//
#include <hip/hip_runtime.h>

#define NC 16384        // num classes == batch
#define FD 128          // feature dim
#define LAMBDA 0.005f
#define SLOTCAP 64      // max samples tracked per class (Poisson(1): max ~10)
#define NPZ 128         // z-gram partials (CHUNK=128 rows each)
#define NPC 256         // c-gram partials (64 classes each)

__device__ __forceinline__ float wave_sum(float v) {
#pragma unroll
  for (int m = 32; m > 0; m >>= 1) v += __shfl_xor(v, m, 64);
  return v;
}

// 64-row gram tile: acc[8][2] += tile^T tile (128x128 out, 8x8 patch/thread)
__device__ __forceinline__ void gram_tile(const float4* t4, int tx, int ty,
                                          float4 acc[8][2]) {
  float4 a0 = t4[ty * 2], a1 = t4[ty * 2 + 1];
  float4 b0 = t4[tx * 2], b1 = t4[tx * 2 + 1];
  for (int r = 0; r < 64; ++r) {
    int rn = (r + 1) & 63;
    float4 na0 = t4[rn * 32 + ty * 2];
    float4 na1 = t4[rn * 32 + ty * 2 + 1];
    float4 nb0 = t4[rn * 32 + tx * 2];
    float4 nb1 = t4[rn * 32 + tx * 2 + 1];
    float av[8] = {a0.x, a0.y, a0.z, a0.w, a1.x, a1.y, a1.z, a1.w};
#pragma unroll
    for (int i = 0; i < 8; ++i) {
      float a = av[i];
      acc[i][0].x += a * b0.x;
      acc[i][0].y += a * b0.y;
      acc[i][0].z += a * b0.z;
      acc[i][0].w += a * b0.w;
      acc[i][1].x += a * b1.x;
      acc[i][1].y += a * b1.y;
      acc[i][1].z += a * b1.z;
      acc[i][1].w += a * b1.w;
    }
    a0 = na0; a1 = na1; b0 = nb0; b1 = nb1;
  }
}

__device__ __forceinline__ void store_partial(float* P, int tx, int ty,
                                              float4 acc[8][2]) {
  int d0 = ty * 8, e0 = tx * 8;
#pragma unroll
  for (int i = 0; i < 8; ++i) {
    *(float4*)&P[(d0 + i) * FD + e0] = acc[i][0];
    *(float4*)&P[(d0 + i) * FD + e0 + 4] = acc[i][1];
  }
}

// --- 0. zero cnt + scal/ticket -----------------------------------------------
__global__ __launch_bounds__(256) void zero_kernel(int4* __restrict__ cnt4,
                                                   float* __restrict__ scal) {
  cnt4[blockIdx.x * 256 + threadIdx.x] = make_int4(0, 0, 0, 0);
  if (blockIdx.x == 0 && threadIdx.x < 16) scal[threadIdx.x] = 0.f;
}

// --- 1. scatter: slot[lab][k] = sample index ----------------------------------
__global__ __launch_bounds__(256) void scatter_kernel(
    const int* __restrict__ labels, int* __restrict__ cnt, int* __restrict__ slot) {
  int i = blockIdx.x * 256 + threadIdx.x;
  int lab = labels[i];
  int p = atomicAdd(&cnt[lab], 1);
  if (p < SLOTCAP) slot[(size_t)lab * SLOTCAP + p] = i;
}

// --- 2. fused: blocks [0,NPC): center+diag+gram_c; [NPC,NPC+NPZ): gram_z ------
__global__ __launch_bounds__(256) void fused_kernel(
    const float* __restrict__ z, const int* __restrict__ cnt,
    const int* __restrict__ slot, float* __restrict__ pz,
    float* __restrict__ pc, float2* __restrict__ dpart) {
  __shared__ float tile[64 * FD];  // 32 KB
  __shared__ float red[8];
  int t = threadIdx.x, wave = t >> 6, lane = t & 63;
  int b = blockIdx.x;
  int tx = t & 15, ty = t >> 4;
  const float4* t4 = (const float4*)tile;

  if (b < NPC) {
    // ---- phase A: gather class sums into registers -> LDS (4 threads/class)
    int base = b * 64;
    int g = t >> 2, j = t & 3;        // group g: class base+g; j: 32-col quarter
    int c = base + g;
    int n = cnt[c];
    if (n > SLOTCAP) n = SLOTCAP;
    float4 racc[8];
#pragma unroll
    for (int q = 0; q < 8; ++q) racc[q] = make_float4(0.f, 0.f, 0.f, 0.f);
    for (int k = 0; k < n; ++k) {
      int i = slot[(size_t)c * SLOTCAP + k];
      const float4* src = (const float4*)&z[(size_t)i * FD + j * 32];
#pragma unroll
      for (int q = 0; q < 8; ++q) {
        float4 v = src[q];
        racc[q].x += v.x; racc[q].y += v.y;
        racc[q].z += v.z; racc[q].w += v.w;
      }
    }
    float inv = n > 0 ? 1.0f / (float)n : 0.0f;
    float4* dst = (float4*)&tile[g * FD + j * 32];
#pragma unroll
    for (int q = 0; q < 8; ++q) {
      racc[q].x *= inv; racc[q].y *= inv;
      racc[q].z *= inv; racc[q].w *= inv;
      dst[q] = racc[q];
    }
    __syncthreads();

    // ---- phase B: normalize centers in LDS + fused diag (16 rows/wave)
    float2* t2 = (float2*)tile;
    float s1 = 0.f, s2 = 0.f;
#pragma unroll
    for (int jj = 0; jj < 16; ++jj) {
      int row = wave * 16 + jj;
      float2 v = t2[row * 64 + lane];
      float ss = wave_sum(v.x * v.x + v.y * v.y);
      float sc = 1.0f / fmaxf(sqrtf(ss), 1e-12f);
      v.x *= sc; v.y *= sc;
      t2[row * 64 + lane] = v;
      float2 a = *(const float2*)&z[(size_t)(base + row) * FD + lane * 2];
      float na = wave_sum(a.x * a.x + a.y * a.y);
      float dd = wave_sum(a.x * v.x + a.y * v.y);
      float d = dd * (1.0f / fmaxf(sqrtf(na), 1e-12f));
      s1 += d; s2 += d * d;
    }
    if (lane == 0) { red[wave * 2] = s1; red[wave * 2 + 1] = s2; }
    __syncthreads();
    if (t == 0) {
      dpart[b] = make_float2(red[0] + red[2] + red[4] + red[6],
                             red[1] + red[3] + red[5] + red[7]);
    }

    // ---- phase C: gram_c partial from the normalized LDS tile
    float4 acc[8][2];
#pragma unroll
    for (int i = 0; i < 8; ++i) {
      acc[i][0] = make_float4(0.f, 0.f, 0.f, 0.f);
      acc[i][1] = make_float4(0.f, 0.f, 0.f, 0.f);
    }
    gram_tile(t4, tx, ty, acc);
    store_partial(&pc[(size_t)b * FD * FD], tx, ty, acc);
  } else {
    // ---- gram_z: 128 rows (2 x 64-row stages), normalize z in LDS
    int b2 = b - NPC;
    float4 acc[8][2];
#pragma unroll
    for (int i = 0; i < 8; ++i) {
      acc[i][0] = make_float4(0.f, 0.f, 0.f, 0.f);
      acc[i][1] = make_float4(0.f, 0.f, 0.f, 0.f);
    }
    for (int s = 0; s < 2; ++s) {
      const float4* src = (const float4*)&z[(size_t)(b2 * 128 + s * 64) * FD];
      float4* dst4 = (float4*)tile;
#pragma unroll
      for (int k = 0; k < 8; ++k) dst4[k * 256 + t] = src[k * 256 + t];
      __syncthreads();
      float2* t2 = (float2*)tile;
#pragma unroll
      for (int jj = 0; jj < 16; ++jj) {
        int row = wave * 16 + jj;
        float2 v = t2[row * 64 + lane];
        float ss = wave_sum(v.x * v.x + v.y * v.y);
        float sc = 1.0f / fmaxf(sqrtf(ss), 1e-12f);
        v.x *= sc; v.y *= sc;
        t2[row * 64 + lane] = v;
      }
      __syncthreads();
      gram_tile(t4, tx, ty, acc);
      __syncthreads();  // protect tile before next stage overwrite
    }
    store_partial(&pz[(size_t)b2 * FD * FD], tx, ty, acc);
  }
}

// --- 3. reduce partials + Frobenius + final loss (last-block ticket) ----------
__global__ __launch_bounds__(256) void reduce_final_kernel(
    const float* __restrict__ pz, const float* __restrict__ pc,
    const float2* __restrict__ dpart, float* __restrict__ scal,
    float* __restrict__ out) {
  __shared__ float lz[4][64], lc[4][64];
  int t = threadIdx.x, wave = t >> 6, lane = t & 63;
  int e = blockIdx.x * 64 + lane;
  float sz = 0.f, sc = 0.f;
#pragma unroll 4
  for (int k = 0; k < NPZ / 4; ++k)
    sz += pz[(size_t)(wave * (NPZ / 4) + k) * (FD * FD) + e];
#pragma unroll 4
  for (int k = 0; k < NPC / 4; ++k)
    sc += pc[(size_t)(wave * (NPC / 4) + k) * (FD * FD) + e];
  lz[wave][lane] = sz;
  lc[wave][lane] = sc;
  __syncthreads();
  if (wave == 0) {
    float tz = lz[0][lane] + lz[1][lane] + lz[2][lane] + lz[3][lane];
    float tc = lc[0][lane] + lc[1][lane] + lc[2][lane] + lc[3][lane];
    float S = wave_sum(tz * tc);
    int* ticket_p = (int*)&scal[8];
    int ticket = 0;
    if (lane == 0) {
      unsafeAtomicAdd(&scal[2], S);
      __threadfence();
      ticket = atomicAdd(ticket_p, 1);
    }
    ticket = __shfl(ticket, 0, 64);
    if (ticket == 255) {  // last block: compose the loss
      float a1 = 0.f, a2 = 0.f;
      for (int k = lane; k < NPC; k += 64) {
        float2 d = dpart[k];
        a1 += d.x; a2 += d.y;
      }
      a1 = wave_sum(a1);
      a2 = wave_sum(a2);
      if (lane == 0) {
        float SS = atomicAdd(&scal[2], 0.0f);  // coherent read of total
        double S1 = a1, S2 = a2, Sall = SS;
        double B = (double)NC;
        double inv_loss = S2 / (B * B) - 2.0 * S1 / B + (double)NC;
        double red_loss = (Sall - S2) / (B * B);
        out[0] = (float)(inv_loss + (double)LAMBDA * red_loss);
      }
    }
  }
}

extern "C" void kernel_launch(void* const* d_in, const int* in_sizes, int n_in,
                              void* d_out, int out_size, void* d_ws, size_t ws_size,
                              hipStream_t stream) {
  const float* z = (const float*)d_in[0];
  const int* labels = (const int*)d_in[1];
  float* out = (float*)d_out;
  float* ws = (float*)d_ws;

  // ws layout (floats):
  // [pz NPZ*FD*FD][pc NPC*FD*FD][dpart 2*NPC][scal 16][cnt NC ints][slot NC*SLOTCAP ints]
  float* pz = ws;
  float* pc = pz + (size_t)NPZ * FD * FD;
  float2* dpart = (float2*)(pc + (size_t)NPC * FD * FD);
  float* scal = (float*)(dpart + NPC);
  int* cnt = (int*)(scal + 16);
  int* slot = cnt + NC;

  zero_kernel<<<NC / 1024, 256, 0, stream>>>((int4*)cnt, scal);
  scatter_kernel<<<NC / 256, 256, 0, stream>>>(labels, cnt, slot);
  fused_kernel<<<NPC + NPZ, 256, 0, stream>>>(z, cnt, slot, pz, pc, dpart);
  reduce_final_kernel<<<FD * FD / 64, 256, 0, stream>>>(pz, pc, dpart, scal, out);
}